// Round 13
// baseline (507.219 us; speedup 1.0000x reference)
//
#include <hip/hip_runtime.h>

typedef _Float16 f16;
typedef _Float16 f16x2 __attribute__((ext_vector_type(2)));
typedef _Float16 f16x4 __attribute__((ext_vector_type(4)));
typedef _Float16 f16x8 __attribute__((ext_vector_type(8)));
typedef float f32x4 __attribute__((ext_vector_type(4)));

#define MFMA_16x16x32(a, b, c) __builtin_amdgcn_mfma_f32_16x16x32_f16((a), (b), (c), 0, 0, 0)

// B=2 S=2048 H=1024 HEADS=16 KD=64 VDIM=2048 HD=128; M=B*S=4096
// qkvg row: [q(1024) | k(1024) | v(2048) | g(2048)] = 6144 cols.
// Chunked retention: C=128, 16 chunks; state R_c[kd][hd] = sum_{t<cC} g^{cC-1-t} k_t v_t^T.

__device__ __forceinline__ void async_ld16(const void* g, void* l) {
  __builtin_amdgcn_global_load_lds((const __attribute__((address_space(1))) unsigned int*)g,
                                   (__attribute__((address_space(3))) unsigned int*)l,
                                   16, 0, 0);
}

// ---------------------------------------------------------------- merged casts
__global__ void k_cast_all(const float* __restrict__ x, const float* __restrict__ Wq,
                           const float* __restrict__ Wk, const float* __restrict__ Wv,
                           const float* __restrict__ Wg, const float* __restrict__ Wo,
                           f16* __restrict__ xh, f16* __restrict__ W1h, f16* __restrict__ Woh) {
  size_t u = ((size_t)blockIdx.x * 256 + threadIdx.x) * 4;
  const float* src;
  f16* dst;
  float sc = 1.0f;
  if (u < 4194304) {                       // x: 4096x1024
    src = x + u; dst = xh + u;
  } else if (u < 10485760) {               // W1: 6144x1024 (q|k|v|g rows)
    size_t idx = u - 4194304;
    int row = (int)(idx >> 10), col = (int)(idx & 1023);
    if (row < 1024)      { src = Wq + (size_t)row * 1024 + col; }
    else if (row < 2048) { src = Wk + (size_t)(row - 1024) * 1024 + col; sc = 0.125f; } // kd^-0.5
    else if (row < 4096) { src = Wv + (size_t)(row - 2048) * 1024 + col; }
    else                 { src = Wg + (size_t)(row - 4096) * 1024 + col; }
    dst = W1h + idx;
  } else {                                 // Wo: 1024x2048
    size_t idx = u - 10485760;
    src = Wo + idx; dst = Woh + idx;
  }
  float4 v = *(const float4*)src;
  f16x4 r = { (f16)(v.x * sc), (f16)(v.y * sc), (f16)(v.z * sc), (f16)(v.w * sc) };
  *(f16x4*)dst = r;
}

// ---------------------------------------------------------------- GEMM 1 (m97 async-staged, proven)
// ROPE: f32-epilogue RoPE on q|k tiles (tile-uniform; pair col^1 = lane^1 via shfl_xor).
template <int NT, bool ROPE, typename OutT>
__global__ __launch_bounds__(256, 3)
void k_gemm_bt(const f16* __restrict__ A, const f16* __restrict__ Bw,
               OutT* __restrict__ C, const float* __restrict__ sinp,
               const float* __restrict__ cosp, int M, int N, int K) {
  __shared__ f16 As[128 * 64];
  __shared__ f16 Bs[NT * 64];
  constexpr int NR = NT / 16;
  const int tid = threadIdx.x;
  const int lane = tid & 63, w = tid >> 6;
  const int quad = lane >> 4, rm = lane & 15;
  const int mt = blockIdx.y, nt = blockIdx.x;
  const f16* Ab = A + (size_t)mt * 128 * K;
  const f16* Bb = Bw + (size_t)nt * NT * K;
  f32x4 acc[2][NR] = {};

  const int sr = lane >> 3;
  const int sc8 = (lane & 7) * 8;

  for (int k0 = 0; k0 < K; k0 += 64) {
    __syncthreads();
#pragma unroll
    for (int p = 0; p < 4; ++p) {
      int br = w * 32 + p * 8;
      async_ld16(Ab + (size_t)(br + sr) * K + k0 + sc8, &As[br * 64]);
    }
#pragma unroll
    for (int p = 0; p < NT / 32; ++p) {
      int br = w * (NT / 4) + p * 8;
      async_ld16(Bb + (size_t)(br + sr) * K + k0 + sc8, &Bs[br * 64]);
    }
    __syncthreads();
#pragma unroll
    for (int kk = 0; kk < 64; kk += 32) {
      const int ko = kk + quad * 8;
      f16x8 a0 = *(const f16x8*)(&As[(w * 32 + rm) * 64 + ko]);
      f16x8 a1 = *(const f16x8*)(&As[(w * 32 + 16 + rm) * 64 + ko]);
#pragma unroll
      for (int n = 0; n < NR; ++n) {
        f16x8 bf = *(const f16x8*)(&Bs[(n * 16 + rm) * 64 + ko]);
        acc[0][n] = MFMA_16x16x32(a0, bf, acc[0][n]);
        acc[1][n] = MFMA_16x16x32(a1, bf, acc[1][n]);
      }
    }
  }
  const bool rope_tile = ROPE && (nt * NT < 2048);
#pragma unroll
  for (int m = 0; m < 2; ++m)
#pragma unroll
    for (int n = 0; n < NR; ++n)
#pragma unroll
      for (int r = 0; r < 4; ++r) {
        int row = mt * 128 + w * 32 + m * 16 + quad * 4 + r;  // C/D: row=quad*4+reg
        int col = nt * NT + n * 16 + rm;                      //      col=lane&15
        float val = acc[m][n][r];
        if (rope_tile) {
          float par = __shfl_xor(val, 1);                     // partner col^1 (lane^1)
          int s = row & 2047;
          int d = col & 63;
          float sv = sinp[s * 64 + d], cv = cosp[s * 64 + d];
          val = (col & 1) ? (val * cv + par * sv) : (val * cv - par * sv);
        }
        C[(size_t)row * N + col] = (OutT)val;
      }
}

// ---------------------------------------------------------------- GEMM 2: 128xM 64xN tile, BK=128
// 32 MFMA per barrier pair (vs 16 at BK=64); LDS 48 KB -> 3 blocks/CU (m132's 64 KB trap avoided).
// Deposit rule (m104): wave-call = 1024 B = 4 rows of 128 f16 -> lane fetches row l>>4, colgrp l&15.
// Same per-accumulator k-order as BK=64 -> bit-exact vs R12.
__global__ __launch_bounds__(256, 3)
void k_gemm2(const f16* __restrict__ A, const f16* __restrict__ Bw,
             float* __restrict__ C, int M, int N, int K) {
  __shared__ f16 As[128 * 128];
  __shared__ f16 Bs[64 * 128];
  const int tid = threadIdx.x;
  const int lane = tid & 63, w = tid >> 6;
  const int quad = lane >> 4, rm = lane & 15;
  const int mt = blockIdx.y, nt = blockIdx.x;
  const f16* Ab = A + (size_t)mt * 128 * K;
  const f16* Bb = Bw + (size_t)nt * 64 * K;
  f32x4 acc[2][4] = {};

  const int sr = lane >> 4;                // 4 rows per wave-call (128-col rows)
  const int sc8 = (lane & 15) * 8;         // col group * 8

  for (int k0 = 0; k0 < K; k0 += 128) {
    __syncthreads();
#pragma unroll
    for (int p = 0; p < 8; ++p) {          // A: wave w stages rows w*32 .. +31 (8 calls x 4 rows)
      int br = w * 32 + p * 4;
      async_ld16(Ab + (size_t)(br + sr) * K + k0 + sc8, &As[br * 128]);
    }
#pragma unroll
    for (int p = 0; p < 4; ++p) {          // B: 64 rows (4 calls x 4 rows per wave)
      int br = w * 16 + p * 4;
      async_ld16(Bb + (size_t)(br + sr) * K + k0 + sc8, &Bs[br * 128]);
    }
    __syncthreads();
#pragma unroll
    for (int kk = 0; kk < 128; kk += 32) {
      const int ko = kk + quad * 8;
      f16x8 a0 = *(const f16x8*)(&As[(w * 32 + rm) * 128 + ko]);
      f16x8 a1 = *(const f16x8*)(&As[(w * 32 + 16 + rm) * 128 + ko]);
#pragma unroll
      for (int n = 0; n < 4; ++n) {
        f16x8 bf = *(const f16x8*)(&Bs[(n * 16 + rm) * 128 + ko]);
        acc[0][n] = MFMA_16x16x32(a0, bf, acc[0][n]);
        acc[1][n] = MFMA_16x16x32(a1, bf, acc[1][n]);
      }
    }
  }
#pragma unroll
  for (int m = 0; m < 2; ++m)
#pragma unroll
    for (int n = 0; n < 4; ++n)
#pragma unroll
      for (int r = 0; r < 4; ++r) {
        int row = mt * 128 + w * 32 + m * 16 + quad * 4 + r;
        int col = nt * 64 + n * 16 + rm;
        C[(size_t)row * N + col] = acc[m][n][r];
      }
}

// ---------------------------------------------------------------- pass A: per-chunk state S_c^T (f16 out)
__device__ __forceinline__ int off136(int d) { return d * 136 + ((d >> 3) << 3); }  // skewed, 16B-aligned

__global__ __launch_bounds__(256, 2)
void k_state(const f16* __restrict__ qkvg, f16* __restrict__ Sws, float* __restrict__ skws) {
  __shared__ f16 Kt[8752];            // Kt[kd][tau], row start off136(kd)
  __shared__ f16 Vt[17520];           // Vt[hd][tau]
  __shared__ float skbuf[4][64];
  const int tid = threadIdx.x;
  const int lane = tid & 63, w = tid >> 6;
  const int quad = lane >> 4, rm = lane & 15;
  const int c = blockIdx.x, h = blockIdx.y, b = blockIdx.z;
  const int bh = b * 16 + h;
  const size_t ld = 6144;
  const f16* base = qkvg + (size_t)b * 2048 * ld + (size_t)c * 128 * ld;
  const float logd = logf(1.0f - exp2f(-5.0f - (float)h));

  // stage K (decayed) transposed: 128 tau x 64 kd
#pragma unroll
  for (int p = 0; p < 4; ++p) {
    int tau = p * 32 + (tid >> 3);
    int kd0 = (tid & 7) * 8;
    f16x8 kv = *(const f16x8*)(base + (size_t)tau * ld + 1024 + h * 64 + kd0);
    float g = expf(logd * (float)(127 - tau));
#pragma unroll
    for (int j = 0; j < 8; ++j) Kt[off136(kd0 + j) + tau] = (f16)((float)kv[j] * g);
  }
  // stage V transposed: 128 tau x 128 hd
#pragma unroll
  for (int p = 0; p < 8; ++p) {
    int tau = p * 16 + (tid >> 4);
    int d0 = (tid & 15) * 8;
    f16x8 vv = *(const f16x8*)(base + (size_t)tau * ld + 2048 + h * 128 + d0);
#pragma unroll
    for (int j = 0; j < 8; ++j) Vt[off136(d0 + j) + tau] = vv[j];
  }
  __syncthreads();

  // S^T = Vt (A: rows=hd) x Kt (B: rows=kd), K-dim = tau(128)
  f32x4 acc[2][4] = {};
#pragma unroll
  for (int kf = 0; kf < 4; ++kf) {
    int k0 = kf * 32 + quad * 8;
    f16x8 av[2];
#pragma unroll
    for (int mm = 0; mm < 2; ++mm)
      av[mm] = *(const f16x8*)(&Vt[off136(w * 32 + mm * 16 + rm) + k0]);
#pragma unroll
    for (int n = 0; n < 4; ++n) {
      f16x8 bk = *(const f16x8*)(&Kt[off136(n * 16 + rm) + k0]);
#pragma unroll
      for (int mm = 0; mm < 2; ++mm) acc[mm][n] = MFMA_16x16x32(av[mm], bk, acc[mm][n]);
    }
  }
  f16* Sout = Sws + ((size_t)c * 32 + bh) * 8192;
#pragma unroll
  for (int mm = 0; mm < 2; ++mm)
#pragma unroll
    for (int n = 0; n < 4; ++n)
#pragma unroll
      for (int r = 0; r < 4; ++r)
        Sout[(w * 32 + mm * 16 + quad * 4 + r) * 64 + n * 16 + rm] = (f16)acc[mm][n][r];

  // sk[kd] = sum_tau Kt[kd][tau]
  {
    int kd = tid & 63;
    float p = 0.f;
    for (int tau = w * 32; tau < w * 32 + 32; ++tau) p += (float)Kt[off136(kd) + tau];
    skbuf[w][kd] = p;
  }
  __syncthreads();
  if (tid < 64) {
    float s = skbuf[0][tid] + skbuf[1][tid] + skbuf[2][tid] + skbuf[3][tid];
    skws[((size_t)c * 32 + bh) * 64 + tid] = s;
  }
}

// ---------------------------------------------------------------- pass B: scan over chunks (256 blocks)
__global__ __launch_bounds__(256, 2)
void k_scan(const f16* __restrict__ Sws, const float* __restrict__ skws,
            f16* __restrict__ Rtws, float* __restrict__ rktws) {
  const int bh = blockIdx.x;
  const int slab = blockIdx.y;
  const int h = bh & 15;
  const int tid = threadIdx.x;
  const float logd = logf(1.0f - exp2f(-5.0f - (float)h));
  const float gC = expf(logd * 128.0f);
  const int idx = slab * 1024 + tid * 4;
  float R[4] = {0.f, 0.f, 0.f, 0.f};
  for (int c = 0; c < 16; ++c) {
    size_t bs = ((size_t)c * 32 + bh) * 8192 + idx;
    f16x4 rv = { (f16)R[0], (f16)R[1], (f16)R[2], (f16)R[3] };
    *(f16x4*)(Rtws + bs) = rv;
    f16x4 sv = *(const f16x4*)(Sws + bs);
#pragma unroll
    for (int i = 0; i < 4; ++i) R[i] = gC * R[i] + (float)sv[i];
  }
  if (slab == 0 && tid < 64) {
    float rk = 0.f;
    for (int c = 0; c < 16; ++c) {
      size_t ks = ((size_t)c * 32 + bh) * 64 + tid;
      rktws[ks] = rk;
      rk = gC * rk + skws[ks];
    }
  }
}

// ---------------------------------------------------------------- pass C: intra-chunk attn + state GEMM
__device__ __forceinline__ int vt_off(int d) { return d * 40 + (d >> 3) * 8; }

__global__ __launch_bounds__(256, 4)
void k_attn(const f16* __restrict__ qkvg, const f16* __restrict__ Rtws,
            const float* __restrict__ rktws, f16* __restrict__ act) {
  constexpr int LDK = 72;
  constexpr int LDP = 40;
  __shared__ f16 Ks[32 * LDK];
  __shared__ f16 Vt[5240];
  __shared__ f16 Ps[4][16 * LDP];
  const int tid = threadIdx.x;
  const int lane = tid & 63, w = tid >> 6;
  const int quad = lane >> 4, rm = lane & 15;
  int bx = blockIdx.x;
  if (blockIdx.z) bx = 31 - bx;
  const int h = blockIdx.y, b = blockIdx.z;
  const int bh = b * 16 + h;
  const int s_blk = bx * 64;
  const int c = s_blk >> 7;
  const size_t ld = 6144;
  const f16* base = qkvg + (size_t)b * 2048 * ld;
  const float logd = logf(1.0f - exp2f(-5.0f - (float)h));

  f16x8 qa[2];
  {
    int row = s_blk + w * 16 + rm;
#pragma unroll
    for (int kh = 0; kh < 2; ++kh)
      qa[kh] = *(const f16x8*)(base + (size_t)row * ld + h * 64 + kh * 32 + quad * 8);
  }
  int voff[8];
#pragma unroll
  for (int n = 0; n < 8; ++n) voff[n] = vt_off(n * 16 + rm) + quad * 8;

  f32x4 od[8];
#pragma unroll
  for (int n = 0; n < 8; ++n) od[n] = (f32x4){0.f, 0.f, 0.f, 0.f};
  float den[4] = {0.f, 0.f, 0.f, 0.f};

  const int tmax = s_blk + 64;
  for (int t0 = c * 128; t0 < tmax; t0 += 32) {
    __syncthreads();
    {
      int r = tid >> 3, cc = (tid & 7) * 8;
      *(uint4*)(&Ks[r * LDK + cc]) =
          *(const uint4*)(base + (size_t)(t0 + r) * ld + 1024 + h * 64 + cc);
    }
#pragma unroll
    for (int p = 0; p < 2; ++p) {
      int t = p * 16 + (tid >> 4);
      int d0 = (tid & 15) * 8;
      f16x8 v = *(const f16x8*)(base + (size_t)(t0 + t) * ld + 2048 + h * 128 + d0);
#pragma unroll
      for (int j = 0; j < 8; ++j) Vt[vt_off(d0 + j) + t] = v[j];
    }
    __syncthreads();

    f32x4 st[2];
#pragma unroll
    for (int ts = 0; ts < 2; ++ts) st[ts] = (f32x4){0.f, 0.f, 0.f, 0.f};
#pragma unroll
    for (int ts = 0; ts < 2; ++ts) {
      f16x8 bk0 = *(const f16x8*)(&Ks[(ts * 16 + rm) * LDK + quad * 8]);
      f16x8 bk1 = *(const f16x8*)(&Ks[(ts * 16 + rm) * LDK + 32 + quad * 8]);
      st[ts] = MFMA_16x16x32(qa[0], bk0, st[ts]);
      st[ts] = MFMA_16x16x32(qa[1], bk1, st[ts]);
    }
#pragma unroll
    for (int ts = 0; ts < 2; ++ts)
#pragma unroll
      for (int r = 0; r < 4; ++r) {
        int s = s_blk + w * 16 + quad * 4 + r;
        int t = t0 + ts * 16 + rm;
        int diff = s - t;
        float pv = 0.f;
        if (diff >= 0) pv = st[ts][r] * expf(logd * (float)diff);
        den[r] += pv;
        Ps[w][(quad * 4 + r) * LDP + ts * 16 + rm] = (f16)pv;
      }
    __syncthreads();
    f16x8 pa = *(const f16x8*)(&Ps[w][rm * LDP + quad * 8]);
#pragma unroll
    for (int n = 0; n < 8; ++n) {
      f16x8 bv = *(const f16x8*)(&Vt[voff[n]]);
      od[n] = MFMA_16x16x32(pa, bv, od[n]);
    }
  }

  // inter-chunk via state: od += (q * g^{ls+1}) @ Rt_c ; den += (q*g) . rk_c
  {
    const f16* Rt = Rtws + ((size_t)c * 32 + bh) * 8192;
    float g1 = expf(logd * (float)(s_blk - c * 128 + w * 16 + rm + 1));
    f16x8 qg[2];
#pragma unroll
    for (int kh = 0; kh < 2; ++kh)
#pragma unroll
      for (int j = 0; j < 8; ++j) qg[kh][j] = (f16)((float)qa[kh][j] * g1);
#pragma unroll
    for (int n = 0; n < 8; ++n) {
      f16x8 b0 = *(const f16x8*)(Rt + (size_t)(n * 16 + rm) * 64 + quad * 8);
      f16x8 b1 = *(const f16x8*)(Rt + (size_t)(n * 16 + rm) * 64 + 32 + quad * 8);
      od[n] = MFMA_16x16x32(qg[0], b0, od[n]);
      od[n] = MFMA_16x16x32(qg[1], b1, od[n]);
    }
    const float* rkp = rktws + ((size_t)c * 32 + bh) * 64;
    f16x8 bd0, bd1;
#pragma unroll
    for (int j = 0; j < 8; ++j) {
      bd0[j] = (rm == 0) ? (f16)rkp[quad * 8 + j] : (f16)0.f;
      bd1[j] = (rm == 0) ? (f16)rkp[32 + quad * 8 + j] : (f16)0.f;
    }
    f32x4 sd = (f32x4){0.f, 0.f, 0.f, 0.f};
    sd = MFMA_16x16x32(qg[0], bd0, sd);
    sd = MFMA_16x16x32(qg[1], bd1, sd);
#pragma unroll
    for (int r = 0; r < 4; ++r) den[r] += sd[r];
  }

  // epilogue: denom -> divide -> RMS(hd=128) -> silu(g) gate -> act
  float dn[4], rr[4];
#pragma unroll
  for (int r = 0; r < 4; ++r) {
    float d = den[r];
    d += __shfl_xor(d, 1, 16);
    d += __shfl_xor(d, 2, 16);
    d += __shfl_xor(d, 4, 16);
    d += __shfl_xor(d, 8, 16);
    dn[r] = fmaxf(fabsf(d), 1.0f);
  }
  float ssq[4] = {0.f, 0.f, 0.f, 0.f};
#pragma unroll
  for (int n = 0; n < 8; ++n)
#pragma unroll
    for (int r = 0; r < 4; ++r) {
      float o = od[n][r] / dn[r];
      od[n][r] = o;
      ssq[r] += o * o;
    }
#pragma unroll
  for (int r = 0; r < 4; ++r) {
    float s2 = ssq[r];
    s2 += __shfl_xor(s2, 1, 16);
    s2 += __shfl_xor(s2, 2, 16);
    s2 += __shfl_xor(s2, 4, 16);
    s2 += __shfl_xor(s2, 8, 16);
    rr[r] = rsqrtf(s2 * (1.0f / 128.0f) + 1e-5f);
  }
#pragma unroll
  for (int n = 0; n < 8; ++n)
#pragma unroll
    for (int r = 0; r < 4; ++r) {
      int s = s_blk + w * 16 + quad * 4 + r;
      int dcol = n * 16 + rm;
      float g = (float)base[(size_t)s * ld + 4096 + h * 128 + dcol];
      float o = od[n][r] * rr[r];
      float a = (g / (1.0f + expf(-g))) * o;
      act[((size_t)b * 2048 + s) * 2048 + h * 128 + dcol] = (f16)a;
    }
}

// ---------------------------------------------------------------- launch
extern "C" void kernel_launch(void* const* d_in, const int* in_sizes, int n_in,
                              void* d_out, int out_size, void* d_ws, size_t ws_size,
                              hipStream_t stream) {
  const float* x    = (const float*)d_in[0];
  const float* sinp = (const float*)d_in[1];
  const float* cosp = (const float*)d_in[2];
  // d_in[3] = mask : recomputed on the fly, never read
  const float* Wq = (const float*)d_in[4];
  const float* Wk = (const float*)d_in[5];
  const float* Wv = (const float*)d_in[6];
  const float* Wg = (const float*)d_in[7];
  const float* Wo = (const float*)d_in[8];
  float* out = (float*)d_out;

  char* ws = (char*)d_ws;
  f16* xh     = (f16*)(ws);                  // 4096*1024
  f16* W1h    = (f16*)(ws + 8388608);        // 6144*1024
  f16* Woh    = (f16*)(ws + 20971520);       // 1024*2048
  f16* qkvg   = (f16*)(ws + 25165824);       // 4096*6144
  f16* acth   = (f16*)(ws + 75497472);       // 4096*2048
  f16* Sws    = (f16*)(ws + 92274688);       // 16*32*8192 f16 = 8.4 MB
  f16* Rtws   = (f16*)(ws + 100663296);      // 16*32*8192 f16 = 8.4 MB
  float* skws = (float*)(ws + 109051904);    // 16*32*64 f32
  float* rktws= (float*)(ws + 109182976);    // 16*32*64 f32

  k_cast_all<<<12288, 256, 0, stream>>>(x, Wq, Wk, Wv, Wg, Wo, xh, W1h, Woh);

  // qkvg = xh @ W1h^T  with fused RoPE on q|k tiles (M=4096, N=6144, K=1024)
  k_gemm_bt<128, true, f16><<<dim3(48, 32), 256, 0, stream>>>(
      xh, W1h, qkvg, sinp, cosp, 4096, 6144, 1024);

  // chunked retention: per-chunk states -> scan -> intra+state attention
  k_state<<<dim3(16, 16, 2), 256, 0, stream>>>(qkvg, Sws, skws);
  k_scan<<<dim3(32, 8), 256, 0, stream>>>(Sws, skws, Rtws, rktws);
  k_attn<<<dim3(32, 16, 2), 256, 0, stream>>>(qkvg, Rtws, rktws, acth);

  // out = acth @ Woh^T  (M=4096, N=1024, K=2048), BK=128
  k_gemm2<<<dim3(16, 32), 256, 0, stream>>>(acth, Woh, out, 4096, 1024, 2048);
}

// Round 14
// 495.806 us; speedup vs baseline: 1.0230x; 1.0230x over previous
//
#include <hip/hip_runtime.h>

typedef _Float16 f16;
typedef _Float16 f16x2 __attribute__((ext_vector_type(2)));
typedef _Float16 f16x4 __attribute__((ext_vector_type(4)));
typedef _Float16 f16x8 __attribute__((ext_vector_type(8)));
typedef float f32x4 __attribute__((ext_vector_type(4)));

#define MFMA_16x16x32(a, b, c) __builtin_amdgcn_mfma_f32_16x16x32_f16((a), (b), (c), 0, 0, 0)

// B=2 S=2048 H=1024 HEADS=16 KD=64 VDIM=2048 HD=128; M=B*S=4096
// qkvg row: [q(1024) | k(1024) | v(2048) | g(2048)] = 6144 cols.
// Chunked retention: C=128, 16 chunks; state R_c[kd][hd] = sum_{t<cC} g^{cC-1-t} k_t v_t^T.

__device__ __forceinline__ void async_ld16(const void* g, void* l) {
  __builtin_amdgcn_global_load_lds((const __attribute__((address_space(1))) unsigned int*)g,
                                   (__attribute__((address_space(3))) unsigned int*)l,
                                   16, 0, 0);
}

// ---------------------------------------------------------------- merged casts
__global__ void k_cast_all(const float* __restrict__ x, const float* __restrict__ Wq,
                           const float* __restrict__ Wk, const float* __restrict__ Wv,
                           const float* __restrict__ Wg, const float* __restrict__ Wo,
                           f16* __restrict__ xh, f16* __restrict__ W1h, f16* __restrict__ Woh) {
  size_t u = ((size_t)blockIdx.x * 256 + threadIdx.x) * 4;
  const float* src;
  f16* dst;
  float sc = 1.0f;
  if (u < 4194304) {                       // x: 4096x1024
    src = x + u; dst = xh + u;
  } else if (u < 10485760) {               // W1: 6144x1024 (q|k|v|g rows)
    size_t idx = u - 4194304;
    int row = (int)(idx >> 10), col = (int)(idx & 1023);
    if (row < 1024)      { src = Wq + (size_t)row * 1024 + col; }
    else if (row < 2048) { src = Wk + (size_t)(row - 1024) * 1024 + col; sc = 0.125f; } // kd^-0.5
    else if (row < 4096) { src = Wv + (size_t)(row - 2048) * 1024 + col; }
    else                 { src = Wg + (size_t)(row - 4096) * 1024 + col; }
    dst = W1h + idx;
  } else {                                 // Wo: 1024x2048
    size_t idx = u - 10485760;
    src = Wo + idx; dst = Woh + idx;
  }
  float4 v = *(const float4*)src;
  f16x4 r = { (f16)(v.x * sc), (f16)(v.y * sc), (f16)(v.z * sc), (f16)(v.w * sc) };
  *(f16x4*)dst = r;
}

// ---------------------------------------------------------------- GEMM (m97 async-staged, R12-proven)
// WPE: waves/EU bound. gemm1 (NT=128, ~164 VGPR) -> 3; gemm2 (NT=64, ~100 VGPR) -> 4
// (latency-bound small tile: residency > barrier amortization — R7/R13 lesson).
// ROPE: f32-epilogue RoPE on q|k tiles (tile-uniform; pair col^1 = lane^1 via shfl_xor).
template <int NT, bool ROPE, int WPE, typename OutT>
__global__ __launch_bounds__(256, WPE)
void k_gemm_bt(const f16* __restrict__ A, const f16* __restrict__ Bw,
               OutT* __restrict__ C, const float* __restrict__ sinp,
               const float* __restrict__ cosp, int M, int N, int K) {
  __shared__ f16 As[128 * 64];
  __shared__ f16 Bs[NT * 64];
  constexpr int NR = NT / 16;
  const int tid = threadIdx.x;
  const int lane = tid & 63, w = tid >> 6;
  const int quad = lane >> 4, rm = lane & 15;
  const int mt = blockIdx.y, nt = blockIdx.x;
  const f16* Ab = A + (size_t)mt * 128 * K;
  const f16* Bb = Bw + (size_t)nt * NT * K;
  f32x4 acc[2][NR] = {};

  const int sr = lane >> 3;
  const int sc8 = (lane & 7) * 8;

  for (int k0 = 0; k0 < K; k0 += 64) {
    __syncthreads();
#pragma unroll
    for (int p = 0; p < 4; ++p) {
      int br = w * 32 + p * 8;
      async_ld16(Ab + (size_t)(br + sr) * K + k0 + sc8, &As[br * 64]);
    }
#pragma unroll
    for (int p = 0; p < NT / 32; ++p) {
      int br = w * (NT / 4) + p * 8;
      async_ld16(Bb + (size_t)(br + sr) * K + k0 + sc8, &Bs[br * 64]);
    }
    __syncthreads();
#pragma unroll
    for (int kk = 0; kk < 64; kk += 32) {
      const int ko = kk + quad * 8;
      f16x8 a0 = *(const f16x8*)(&As[(w * 32 + rm) * 64 + ko]);
      f16x8 a1 = *(const f16x8*)(&As[(w * 32 + 16 + rm) * 64 + ko]);
#pragma unroll
      for (int n = 0; n < NR; ++n) {
        f16x8 bf = *(const f16x8*)(&Bs[(n * 16 + rm) * 64 + ko]);
        acc[0][n] = MFMA_16x16x32(a0, bf, acc[0][n]);
        acc[1][n] = MFMA_16x16x32(a1, bf, acc[1][n]);
      }
    }
  }
  const bool rope_tile = ROPE && (nt * NT < 2048);
#pragma unroll
  for (int m = 0; m < 2; ++m)
#pragma unroll
    for (int n = 0; n < NR; ++n)
#pragma unroll
      for (int r = 0; r < 4; ++r) {
        int row = mt * 128 + w * 32 + m * 16 + quad * 4 + r;  // C/D: row=quad*4+reg
        int col = nt * NT + n * 16 + rm;                      //      col=lane&15
        float val = acc[m][n][r];
        if (rope_tile) {
          float par = __shfl_xor(val, 1);                     // partner col^1 (lane^1)
          int s = row & 2047;
          int d = col & 63;
          float sv = sinp[s * 64 + d], cv = cosp[s * 64 + d];
          val = (col & 1) ? (val * cv + par * sv) : (val * cv - par * sv);
        }
        C[(size_t)row * N + col] = (OutT)val;
      }
}

// ---------------------------------------------------------------- pass A: per-chunk state S_c^T (f16 out)
__device__ __forceinline__ int off136(int d) { return d * 136 + ((d >> 3) << 3); }  // skewed, 16B-aligned

__global__ __launch_bounds__(256, 2)
void k_state(const f16* __restrict__ qkvg, f16* __restrict__ Sws, float* __restrict__ skws) {
  __shared__ f16 Kt[8752];            // Kt[kd][tau], row start off136(kd)
  __shared__ f16 Vt[17520];           // Vt[hd][tau]
  __shared__ float skbuf[4][64];
  const int tid = threadIdx.x;
  const int lane = tid & 63, w = tid >> 6;
  const int quad = lane >> 4, rm = lane & 15;
  const int c = blockIdx.x, h = blockIdx.y, b = blockIdx.z;
  const int bh = b * 16 + h;
  const size_t ld = 6144;
  const f16* base = qkvg + (size_t)b * 2048 * ld + (size_t)c * 128 * ld;
  const float logd = logf(1.0f - exp2f(-5.0f - (float)h));

  // stage K (decayed) transposed: 128 tau x 64 kd
#pragma unroll
  for (int p = 0; p < 4; ++p) {
    int tau = p * 32 + (tid >> 3);
    int kd0 = (tid & 7) * 8;
    f16x8 kv = *(const f16x8*)(base + (size_t)tau * ld + 1024 + h * 64 + kd0);
    float g = expf(logd * (float)(127 - tau));
#pragma unroll
    for (int j = 0; j < 8; ++j) Kt[off136(kd0 + j) + tau] = (f16)((float)kv[j] * g);
  }
  // stage V transposed: 128 tau x 128 hd
#pragma unroll
  for (int p = 0; p < 8; ++p) {
    int tau = p * 16 + (tid >> 4);
    int d0 = (tid & 15) * 8;
    f16x8 vv = *(const f16x8*)(base + (size_t)tau * ld + 2048 + h * 128 + d0);
#pragma unroll
    for (int j = 0; j < 8; ++j) Vt[off136(d0 + j) + tau] = vv[j];
  }
  __syncthreads();

  // S^T = Vt (A: rows=hd) x Kt (B: rows=kd), K-dim = tau(128)
  f32x4 acc[2][4] = {};
#pragma unroll
  for (int kf = 0; kf < 4; ++kf) {
    int k0 = kf * 32 + quad * 8;
    f16x8 av[2];
#pragma unroll
    for (int mm = 0; mm < 2; ++mm)
      av[mm] = *(const f16x8*)(&Vt[off136(w * 32 + mm * 16 + rm) + k0]);
#pragma unroll
    for (int n = 0; n < 4; ++n) {
      f16x8 bk = *(const f16x8*)(&Kt[off136(n * 16 + rm) + k0]);
#pragma unroll
      for (int mm = 0; mm < 2; ++mm) acc[mm][n] = MFMA_16x16x32(av[mm], bk, acc[mm][n]);
    }
  }
  f16* Sout = Sws + ((size_t)c * 32 + bh) * 8192;
#pragma unroll
  for (int mm = 0; mm < 2; ++mm)
#pragma unroll
    for (int n = 0; n < 4; ++n)
#pragma unroll
      for (int r = 0; r < 4; ++r)
        Sout[(w * 32 + mm * 16 + quad * 4 + r) * 64 + n * 16 + rm] = (f16)acc[mm][n][r];

  // sk[kd] = sum_tau Kt[kd][tau]
  {
    int kd = tid & 63;
    float p = 0.f;
    for (int tau = w * 32; tau < w * 32 + 32; ++tau) p += (float)Kt[off136(kd) + tau];
    skbuf[w][kd] = p;
  }
  __syncthreads();
  if (tid < 64) {
    float s = skbuf[0][tid] + skbuf[1][tid] + skbuf[2][tid] + skbuf[3][tid];
    skws[((size_t)c * 32 + bh) * 64 + tid] = s;
  }
}

// ---------------------------------------------------------------- pass B: scan over chunks (256 blocks)
__global__ __launch_bounds__(256, 2)
void k_scan(const f16* __restrict__ Sws, const float* __restrict__ skws,
            f16* __restrict__ Rtws, float* __restrict__ rktws) {
  const int bh = blockIdx.x;
  const int slab = blockIdx.y;
  const int h = bh & 15;
  const int tid = threadIdx.x;
  const float logd = logf(1.0f - exp2f(-5.0f - (float)h));
  const float gC = expf(logd * 128.0f);
  const int idx = slab * 1024 + tid * 4;
  float R[4] = {0.f, 0.f, 0.f, 0.f};
  for (int c = 0; c < 16; ++c) {
    size_t bs = ((size_t)c * 32 + bh) * 8192 + idx;
    f16x4 rv = { (f16)R[0], (f16)R[1], (f16)R[2], (f16)R[3] };
    *(f16x4*)(Rtws + bs) = rv;
    f16x4 sv = *(const f16x4*)(Sws + bs);
#pragma unroll
    for (int i = 0; i < 4; ++i) R[i] = gC * R[i] + (float)sv[i];
  }
  if (slab == 0 && tid < 64) {
    float rk = 0.f;
    for (int c = 0; c < 16; ++c) {
      size_t ks = ((size_t)c * 32 + bh) * 64 + tid;
      rktws[ks] = rk;
      rk = gC * rk + skws[ks];
    }
  }
}

// ---------------------------------------------------------------- pass C: intra-chunk attn + state GEMM
__device__ __forceinline__ int vt_off(int d) { return d * 40 + (d >> 3) * 8; }

__global__ __launch_bounds__(256, 4)
void k_attn(const f16* __restrict__ qkvg, const f16* __restrict__ Rtws,
            const float* __restrict__ rktws, f16* __restrict__ act) {
  constexpr int LDK = 72;
  constexpr int LDP = 40;
  __shared__ f16 Ks[32 * LDK];
  __shared__ f16 Vt[5240];
  __shared__ f16 Ps[4][16 * LDP];
  const int tid = threadIdx.x;
  const int lane = tid & 63, w = tid >> 6;
  const int quad = lane >> 4, rm = lane & 15;
  int bx = blockIdx.x;
  if (blockIdx.z) bx = 31 - bx;
  const int h = blockIdx.y, b = blockIdx.z;
  const int bh = b * 16 + h;
  const int s_blk = bx * 64;
  const int c = s_blk >> 7;
  const size_t ld = 6144;
  const f16* base = qkvg + (size_t)b * 2048 * ld;
  const float logd = logf(1.0f - exp2f(-5.0f - (float)h));

  f16x8 qa[2];
  {
    int row = s_blk + w * 16 + rm;
#pragma unroll
    for (int kh = 0; kh < 2; ++kh)
      qa[kh] = *(const f16x8*)(base + (size_t)row * ld + h * 64 + kh * 32 + quad * 8);
  }
  int voff[8];
#pragma unroll
  for (int n = 0; n < 8; ++n) voff[n] = vt_off(n * 16 + rm) + quad * 8;

  f32x4 od[8];
#pragma unroll
  for (int n = 0; n < 8; ++n) od[n] = (f32x4){0.f, 0.f, 0.f, 0.f};
  float den[4] = {0.f, 0.f, 0.f, 0.f};

  const int tmax = s_blk + 64;
  for (int t0 = c * 128; t0 < tmax; t0 += 32) {
    __syncthreads();
    {
      int r = tid >> 3, cc = (tid & 7) * 8;
      *(uint4*)(&Ks[r * LDK + cc]) =
          *(const uint4*)(base + (size_t)(t0 + r) * ld + 1024 + h * 64 + cc);
    }
#pragma unroll
    for (int p = 0; p < 2; ++p) {
      int t = p * 16 + (tid >> 4);
      int d0 = (tid & 15) * 8;
      f16x8 v = *(const f16x8*)(base + (size_t)(t0 + t) * ld + 2048 + h * 128 + d0);
#pragma unroll
      for (int j = 0; j < 8; ++j) Vt[vt_off(d0 + j) + t] = v[j];
    }
    __syncthreads();

    f32x4 st[2];
#pragma unroll
    for (int ts = 0; ts < 2; ++ts) st[ts] = (f32x4){0.f, 0.f, 0.f, 0.f};
#pragma unroll
    for (int ts = 0; ts < 2; ++ts) {
      f16x8 bk0 = *(const f16x8*)(&Ks[(ts * 16 + rm) * LDK + quad * 8]);
      f16x8 bk1 = *(const f16x8*)(&Ks[(ts * 16 + rm) * LDK + 32 + quad * 8]);
      st[ts] = MFMA_16x16x32(qa[0], bk0, st[ts]);
      st[ts] = MFMA_16x16x32(qa[1], bk1, st[ts]);
    }
#pragma unroll
    for (int ts = 0; ts < 2; ++ts)
#pragma unroll
      for (int r = 0; r < 4; ++r) {
        int s = s_blk + w * 16 + quad * 4 + r;
        int t = t0 + ts * 16 + rm;
        int diff = s - t;
        float pv = 0.f;
        if (diff >= 0) pv = st[ts][r] * expf(logd * (float)diff);
        den[r] += pv;
        Ps[w][(quad * 4 + r) * LDP + ts * 16 + rm] = (f16)pv;
      }
    __syncthreads();
    f16x8 pa = *(const f16x8*)(&Ps[w][rm * LDP + quad * 8]);
#pragma unroll
    for (int n = 0; n < 8; ++n) {
      f16x8 bv = *(const f16x8*)(&Vt[voff[n]]);
      od[n] = MFMA_16x16x32(pa, bv, od[n]);
    }
  }

  // inter-chunk via state: od += (q * g^{ls+1}) @ Rt_c ; den += (q*g) . rk_c
  {
    const f16* Rt = Rtws + ((size_t)c * 32 + bh) * 8192;
    float g1 = expf(logd * (float)(s_blk - c * 128 + w * 16 + rm + 1));
    f16x8 qg[2];
#pragma unroll
    for (int kh = 0; kh < 2; ++kh)
#pragma unroll
      for (int j = 0; j < 8; ++j) qg[kh][j] = (f16)((float)qa[kh][j] * g1);
#pragma unroll
    for (int n = 0; n < 8; ++n) {
      f16x8 b0 = *(const f16x8*)(Rt + (size_t)(n * 16 + rm) * 64 + quad * 8);
      f16x8 b1 = *(const f16x8*)(Rt + (size_t)(n * 16 + rm) * 64 + 32 + quad * 8);
      od[n] = MFMA_16x16x32(qg[0], b0, od[n]);
      od[n] = MFMA_16x16x32(qg[1], b1, od[n]);
    }
    const float* rkp = rktws + ((size_t)c * 32 + bh) * 64;
    f16x8 bd0, bd1;
#pragma unroll
    for (int j = 0; j < 8; ++j) {
      bd0[j] = (rm == 0) ? (f16)rkp[quad * 8 + j] : (f16)0.f;
      bd1[j] = (rm == 0) ? (f16)rkp[32 + quad * 8 + j] : (f16)0.f;
    }
    f32x4 sd = (f32x4){0.f, 0.f, 0.f, 0.f};
    sd = MFMA_16x16x32(qg[0], bd0, sd);
    sd = MFMA_16x16x32(qg[1], bd1, sd);
#pragma unroll
    for (int r = 0; r < 4; ++r) den[r] += sd[r];
  }

  // epilogue: denom -> divide -> RMS(hd=128) -> silu(g) gate -> act
  float dn[4], rr[4];
#pragma unroll
  for (int r = 0; r < 4; ++r) {
    float d = den[r];
    d += __shfl_xor(d, 1, 16);
    d += __shfl_xor(d, 2, 16);
    d += __shfl_xor(d, 4, 16);
    d += __shfl_xor(d, 8, 16);
    dn[r] = fmaxf(fabsf(d), 1.0f);
  }
  float ssq[4] = {0.f, 0.f, 0.f, 0.f};
#pragma unroll
  for (int n = 0; n < 8; ++n)
#pragma unroll
    for (int r = 0; r < 4; ++r) {
      float o = od[n][r] / dn[r];
      od[n][r] = o;
      ssq[r] += o * o;
    }
#pragma unroll
  for (int r = 0; r < 4; ++r) {
    float s2 = ssq[r];
    s2 += __shfl_xor(s2, 1, 16);
    s2 += __shfl_xor(s2, 2, 16);
    s2 += __shfl_xor(s2, 4, 16);
    s2 += __shfl_xor(s2, 8, 16);
    rr[r] = rsqrtf(s2 * (1.0f / 128.0f) + 1e-5f);
  }
#pragma unroll
  for (int n = 0; n < 8; ++n)
#pragma unroll
    for (int r = 0; r < 4; ++r) {
      int s = s_blk + w * 16 + quad * 4 + r;
      int dcol = n * 16 + rm;
      float g = (float)base[(size_t)s * ld + 4096 + h * 128 + dcol];
      float o = od[n][r] * rr[r];
      float a = (g / (1.0f + expf(-g))) * o;
      act[((size_t)b * 2048 + s) * 2048 + h * 128 + dcol] = (f16)a;
    }
}

// ---------------------------------------------------------------- launch
extern "C" void kernel_launch(void* const* d_in, const int* in_sizes, int n_in,
                              void* d_out, int out_size, void* d_ws, size_t ws_size,
                              hipStream_t stream) {
  const float* x    = (const float*)d_in[0];
  const float* sinp = (const float*)d_in[1];
  const float* cosp = (const float*)d_in[2];
  // d_in[3] = mask : recomputed on the fly, never read
  const float* Wq = (const float*)d_in[4];
  const float* Wk = (const float*)d_in[5];
  const float* Wv = (const float*)d_in[6];
  const float* Wg = (const float*)d_in[7];
  const float* Wo = (const float*)d_in[8];
  float* out = (float*)d_out;

  char* ws = (char*)d_ws;
  f16* xh     = (f16*)(ws);                  // 4096*1024
  f16* W1h    = (f16*)(ws + 8388608);        // 6144*1024
  f16* Woh    = (f16*)(ws + 20971520);       // 1024*2048
  f16* qkvg   = (f16*)(ws + 25165824);       // 4096*6144
  f16* acth   = (f16*)(ws + 75497472);       // 4096*2048
  f16* Sws    = (f16*)(ws + 92274688);       // 16*32*8192 f16 = 8.4 MB
  f16* Rtws   = (f16*)(ws + 100663296);      // 16*32*8192 f16 = 8.4 MB
  float* skws = (float*)(ws + 109051904);    // 16*32*64 f32
  float* rktws= (float*)(ws + 109182976);    // 16*32*64 f32

  k_cast_all<<<12288, 256, 0, stream>>>(x, Wq, Wk, Wv, Wg, Wo, xh, W1h, Woh);

  // qkvg = xh @ W1h^T  with fused RoPE on q|k tiles (M=4096, N=6144, K=1024)
  k_gemm_bt<128, true, 3, f16><<<dim3(48, 32), 256, 0, stream>>>(
      xh, W1h, qkvg, sinp, cosp, 4096, 6144, 1024);

  // chunked retention: per-chunk states -> scan -> intra+state attention
  k_state<<<dim3(16, 16, 2), 256, 0, stream>>>(qkvg, Sws, skws);
  k_scan<<<dim3(32, 8), 256, 0, stream>>>(Sws, skws, Rtws, rktws);
  k_attn<<<dim3(32, 16, 2), 256, 0, stream>>>(qkvg, Rtws, rktws, acth);

  // out = acth @ Woh^T  (M=4096, N=1024, K=2048), BK=64, 4 blocks/CU
  k_gemm_bt<64, false, 4, float><<<dim3(16, 32), 256, 0, stream>>>(
      acth, Woh, out, nullptr, nullptr, 4096, 1024, 2048);
}